// Round 7
// baseline (284.415 us; speedup 1.0000x reference)
//
#include <hip/hip_runtime.h>
#include <math.h>

// Problem constants (match reference)
#define NQ 16384
#define NK 7933
#define DI 1024
#define HD 512
#define RANK_TARGET 11469   // NQ - int(0.3*NQ): 0-based ascending rank of thre

typedef __bf16 bf16x8 __attribute__((ext_vector_type(8)));
typedef float  f32x4  __attribute__((ext_vector_type(4)));

#define GLOAD_LDS16(g, l)                                                     \
  __builtin_amdgcn_global_load_lds(                                           \
      (const __attribute__((address_space(1))) void*)(g),                     \
      (__attribute__((address_space(3))) void*)(l), 16, 0, 0)

__device__ __forceinline__ unsigned mapf(float f) {
  unsigned b = __float_as_uint(f);
  return (b & 0x80000000u) ? ~b : (b | 0x80000000u);
}
__device__ __forceinline__ float unmapf(unsigned key) {
  unsigned bits = (key & 0x80000000u) ? (key ^ 0x80000000u) : ~key;
  return __uint_as_float(bits);
}

// ---------------------------------------------------------------------------
// Node 1: fp32 -> bf16 for query, key, wq_w, wk_w. Block 0 zeroes v/z/scf.
// ---------------------------------------------------------------------------
__global__ void conv_all(const float* __restrict__ q, const float* __restrict__ k,
                         const float* __restrict__ wq, const float* __restrict__ wk,
                         __bf16* __restrict__ qbf, __bf16* __restrict__ kbf,
                         __bf16* __restrict__ wqbf, __bf16* __restrict__ wkbf,
                         unsigned* __restrict__ zero_region) {
  if (blockIdx.x == 0) {
    for (int j = threadIdx.x; j < 1088; j += 256) zero_region[j] = 0u;
  }
  const int NQ8 = NQ * DI / 8;
  const int NK8 = NK * DI / 8;
  const int W8  = HD * DI / 8;
  const int total = NQ8 + NK8 + 2 * W8;
  int i = blockIdx.x * blockDim.x + threadIdx.x;
  int stride = gridDim.x * blockDim.x;
  for (; i < total; i += stride) {
    const float* s; __bf16* d; int j;
    if (i < NQ8)                 { s = q;  d = qbf;  j = i; }
    else if (i < NQ8 + NK8)      { s = k;  d = kbf;  j = i - NQ8; }
    else if (i < NQ8 + NK8 + W8) { s = wq; d = wqbf; j = i - NQ8 - NK8; }
    else                         { s = wk; d = wkbf; j = i - NQ8 - NK8 - W8; }
    float4 a = ((const float4*)s)[2 * j];
    float4 b = ((const float4*)s)[2 * j + 1];
    bf16x8 o;
    o[0] = (__bf16)a.x; o[1] = (__bf16)a.y; o[2] = (__bf16)a.z; o[3] = (__bf16)a.w;
    o[4] = (__bf16)b.x; o[5] = (__bf16)b.y; o[6] = (__bf16)b.z; o[7] = (__bf16)b.w;
    ((bf16x8*)d)[j] = o;
  }
}

// ---------------------------------------------------------------------------
// Nodes 2 & 4: C[M,512] = tanh(A[M,1024] @ B[512,1024]^T + bias), bf16->f32.
// 128x128 tile, BK=64, global_load_lds width-16, XOR-swizzled LDS
// (conflicts measured 0 in r5). launch_bounds (256,2): grid is exactly
// 2 blocks/CU; the (256,3) bound squeezed VGPR 76->64 and halved MfmaUtil.
// FUSE_A1: epilogue accumulates A1dot[r] += sum(tanh*v[col]) and
// A1ss[r] += sum(tanh^2) via 16-lane shuffle reduce + 2 atomics per row.
// ---------------------------------------------------------------------------
template <bool FUSE_A1>
__global__ __launch_bounds__(256, 2)
void gemm_bt_tanh(const __bf16* __restrict__ A, const __bf16* __restrict__ B,
                  const float* __restrict__ bias, float* __restrict__ C, int M,
                  const float* __restrict__ v, float* __restrict__ A1dot,
                  float* __restrict__ A1ss) {
  constexpr int K = DI;
  constexpr int N = HD;
  __shared__ __align__(16) __bf16 sA[128 * 64];
  __shared__ __align__(16) __bf16 sB[128 * 64];

  const int tid  = threadIdx.x;
  const int lane = tid & 63;
  const int wave = tid >> 6;
  const int wr = wave >> 1, wc = wave & 1;
  const int m0 = blockIdx.x * 128, n0 = blockIdx.y * 128;

  const int srow = lane >> 3;                   // 0..7 row within segment
  const int scol = (((lane & 7) ^ srow)) << 3;  // swizzled col (bf16 units)

  const int lrow = lane & 15;
  const int chi  = lane >> 4;                   // 0..3 chunk offset from ks

  f32x4 acc[4][4] = {};

  for (int kk = 0; kk < K; kk += 64) {
    __syncthreads();
#pragma unroll
    for (int c = 0; c < 4; ++c) {
      int seg = wave * 4 + c;             // 0..15, wave-uniform
      int row = seg * 8 + srow;           // 0..127
      int ga = m0 + row; if (ga > M - 1) ga = M - 1;  // clamp tail
      GLOAD_LDS16(A + (size_t)ga * K + kk + scol, &sA[seg * 512]);
      GLOAD_LDS16(B + (size_t)(n0 + row) * K + kk + scol, &sB[seg * 512]);
    }
    __syncthreads();
#pragma unroll
    for (int ks = 0; ks < 64; ks += 32) {
      const int cc = (ks >> 3) + chi;                  // logical 16B chunk
      const int sw = ((cc ^ (lrow & 7)) << 3);         // swizzled bf16 offset
      bf16x8 af[4], bfr[4];
#pragma unroll
      for (int mi = 0; mi < 4; ++mi)
        af[mi] = *(const bf16x8*)(&sA[(wr * 64 + mi * 16 + lrow) * 64 + sw]);
#pragma unroll
      for (int ni = 0; ni < 4; ++ni)
        bfr[ni] = *(const bf16x8*)(&sB[(wc * 64 + ni * 16 + lrow) * 64 + sw]);
#pragma unroll
      for (int mi = 0; mi < 4; ++mi)
#pragma unroll
        for (int ni = 0; ni < 4; ++ni)
          acc[mi][ni] = __builtin_amdgcn_mfma_f32_16x16x32_bf16(af[mi], bfr[ni], acc[mi][ni], 0, 0, 0);
    }
  }

  // C/D layout: row = (lane>>4)*4 + reg, col = lane&15  [learn_hip m89]
  const int rbase = m0 + wr * 64 + ((lane >> 4) << 2);
  const int cbase = n0 + wc * 64 + (lane & 15);
  float b4[4], v4[4];
#pragma unroll
  for (int ni = 0; ni < 4; ++ni) {
    b4[ni] = bias[cbase + ni * 16];
    if constexpr (FUSE_A1) v4[ni] = v[cbase + ni * 16];
  }
#pragma unroll
  for (int mi = 0; mi < 4; ++mi) {
#pragma unroll
    for (int r = 0; r < 4; ++r) {
      int grow = rbase + mi * 16 + r;
      if (grow < M) {
        float pd = 0.f, pss = 0.f;
#pragma unroll
        for (int ni = 0; ni < 4; ++ni) {
          float val = tanhf(acc[mi][ni][r] + b4[ni]);
          C[(size_t)grow * N + cbase + ni * 16] = val;
          if constexpr (FUSE_A1) { pd += val * v4[ni]; pss += val * val; }
        }
        if constexpr (FUSE_A1) {
#pragma unroll
          for (int off = 1; off < 16; off <<= 1) {
            pd += __shfl_xor(pd, off);
            pss += __shfl_xor(pss, off);
          }
          if ((lane & 15) == 0) {
            atomicAdd(&A1dot[grow], pd);
            atomicAdd(&A1ss[grow], pss);
          }
        }
      }
    }
  }
}

// ---------------------------------------------------------------------------
// Node 3: v[512] = sum_k wa[k]*ktanh[k,:]/max(||ktanh[k,:]||,1e-12).
// Also zeroes A1dot/A1ss scratch (128 KB as 16384 uint2 over 64 blocks).
// ---------------------------------------------------------------------------
__global__ __launch_bounds__(256)
void reduce_v_zero(const float* __restrict__ kt, const float* __restrict__ wa,
                   float* __restrict__ v, int M, uint2* __restrict__ zr) {
  {
    int g = blockIdx.x * 256 + threadIdx.x;           // 64 blocks -> 16384
    uint2 zz; zz.x = 0u; zz.y = 0u;
    zr[g] = zz;
  }
  __shared__ float vpart[4][512];
  const int tid = threadIdx.x, lane = tid & 63, wave = tid >> 6;
  const int gw = blockIdx.x * 4 + wave;
  const int tw = gridDim.x * 4;
  float acc[8] = {0, 0, 0, 0, 0, 0, 0, 0};
  for (int r = gw; r < M; r += tw) {
    const float4* p = (const float4*)(kt + (size_t)r * HD + lane * 8);
    float4 x = p[0], y = p[1];
    float ss = x.x * x.x + x.y * x.y + x.z * x.z + x.w * x.w
             + y.x * y.x + y.y * y.y + y.z * y.z + y.w * y.w;
#pragma unroll
    for (int off = 32; off; off >>= 1) ss += __shfl_xor(ss, off);
    float s = wa[r] / fmaxf(sqrtf(ss), 1e-12f);
    acc[0] += s * x.x; acc[1] += s * x.y; acc[2] += s * x.z; acc[3] += s * x.w;
    acc[4] += s * y.x; acc[5] += s * y.y; acc[6] += s * y.z; acc[7] += s * y.w;
  }
#pragma unroll
  for (int j = 0; j < 8; ++j) vpart[wave][lane * 8 + j] = acc[j];
  __syncthreads();
  for (int c = tid; c < 512; c += 256)
    atomicAdd(&v[c], vpart[0][c] + vpart[1][c] + vpart[2][c] + vpart[3][c]);
}

// ---------------------------------------------------------------------------
// Node 5: single block, 1024 threads. Finalize A1 from A1dot/A1ss, exact
// rank-11469 select via 16 rounds of 2-bit greedy MSB binary search over
// register-resident keys, then S = sum exp(thr(A1)-thre) in the same block.
// scf[0] = thre, scf[2] = S.
// ---------------------------------------------------------------------------
__global__ __launch_bounds__(1024)
void select_kernel(const float* __restrict__ A1dot, const float* __restrict__ A1ss,
                   const float* __restrict__ wa_b, float* __restrict__ A1,
                   float* __restrict__ scf) {
  __shared__ unsigned wred1[16], wred2[16], wred3[16];
  __shared__ float fred[16];
  __shared__ unsigned s_res;
  const int t = threadIdx.x, lane = t & 63, wave = t >> 6;
  const float wab = wa_b[0];
  unsigned kloc[16];
#pragma unroll 4
  for (int j = 0; j < 16; ++j) {
    int i = j * 1024 + t;
    float d = A1dot[i], ss = A1ss[i];
    float a1 = d / fmaxf(sqrtf(ss), 1e-12f) + wab;
    A1[i] = a1;
    kloc[j] = mapf(a1);
  }
  if (t == 0) s_res = 0u;
  __syncthreads();

  for (int b = 30; b >= 0; b -= 2) {
    const unsigned res = s_res;
    const unsigned t1 = res | (1u << b);
    const unsigned t2 = res | (2u << b);
    const unsigned t3 = res | (3u << b);
    unsigned c1 = 0, c2 = 0, c3 = 0;
#pragma unroll
    for (int j = 0; j < 16; ++j) {
      unsigned k = kloc[j];
      c1 += (k < t1); c2 += (k < t2); c3 += (k < t3);
    }
#pragma unroll
    for (int off = 32; off; off >>= 1) {
      c1 += __shfl_xor(c1, off);
      c2 += __shfl_xor(c2, off);
      c3 += __shfl_xor(c3, off);
    }
    if (lane == 0) { wred1[wave] = c1; wred2[wave] = c2; wred3[wave] = c3; }
    __syncthreads();
    if (t == 0) {
      unsigned C1 = 0, C2 = 0, C3 = 0;
      for (int w = 0; w < 16; ++w) { C1 += wred1[w]; C2 += wred2[w]; C3 += wred3[w]; }
      unsigned nr = res;
      if (C3 <= RANK_TARGET)      nr = t3;
      else if (C2 <= RANK_TARGET) nr = t2;
      else if (C1 <= RANK_TARGET) nr = t1;
      s_res = nr;
    }
    __syncthreads();
  }
  // thre known to all threads; compute S in-block from register keys
  const float thre = unmapf(s_res);
  float es = 0.f;
#pragma unroll
  for (int j = 0; j < 16; ++j) {
    float x = unmapf(kloc[j]);
    x = (x > thre) ? x : 0.f;
    es += expf(x - thre);
  }
#pragma unroll
  for (int off = 32; off; off >>= 1) es += __shfl_xor(es, off);
  if (lane == 0) fred[wave] = es;
  __syncthreads();
  if (t == 0) {
    float S = 0.f;
    for (int w = 0; w < 16; ++w) S += fred[w];
    scf[0] = thre;
    scf[2] = S;
  }
}

// ---------------------------------------------------------------------------
// Node 6: attn[r] = exp(thr(A1[r]) - thre)/S (final, normalized);
// z[c] += attn[r]*qt[r,c]; LAST block (arrival counter) computes
// y = z . cls_w + cls_b.  Grid = 128 blocks.
// ---------------------------------------------------------------------------
__global__ __launch_bounds__(256)
void expz(const float* __restrict__ A1, const float* __restrict__ qt,
          float* __restrict__ scf, float* __restrict__ out_attn,
          float* __restrict__ z, const float* __restrict__ cls_w,
          const float* __restrict__ cls_b, float* __restrict__ out_y) {
  __shared__ float vpart[4][512];
  __shared__ int s_last;
  const int tid = threadIdx.x, lane = tid & 63, wave = tid >> 6;
  const float thre = scf[0], invZ = 1.f / scf[2];
  const int gw = blockIdx.x * 4 + wave;
  const int tw = gridDim.x * 4;
  float acc[8] = {0, 0, 0, 0, 0, 0, 0, 0};
  for (int r = gw; r < NQ; r += tw) {
    float x = A1[r]; x = (x > thre) ? x : 0.f;
    float a = expf(x - thre) * invZ;
    if (lane == 0) out_attn[r] = a;
    const float4* p = (const float4*)(qt + (size_t)r * HD + lane * 8);
    float4 u = p[0], w = p[1];
    acc[0] += a * u.x; acc[1] += a * u.y; acc[2] += a * u.z; acc[3] += a * u.w;
    acc[4] += a * w.x; acc[5] += a * w.y; acc[6] += a * w.z; acc[7] += a * w.w;
  }
#pragma unroll
  for (int j = 0; j < 8; ++j) vpart[wave][lane * 8 + j] = acc[j];
  __syncthreads();
  for (int c = tid; c < 512; c += 256)
    atomicAdd(&z[c], vpart[0][c] + vpart[1][c] + vpart[2][c] + vpart[3][c]);

  // last-block pattern: barrier drains this block's atomics; counter in scf[3]
  __syncthreads();
  if (tid == 0) {
    __threadfence();
    unsigned prev = __hip_atomic_fetch_add((unsigned*)&scf[3], 1u,
                                           __ATOMIC_ACQ_REL, __HIP_MEMORY_SCOPE_AGENT);
    s_last = (prev == (unsigned)(gridDim.x - 1));
  }
  __syncthreads();
  if (s_last && wave == 0) {
    float dot = 0.f;
#pragma unroll
    for (int j = 0; j < 8; ++j) {
      float zz = __hip_atomic_load(&z[lane * 8 + j], __ATOMIC_RELAXED,
                                   __HIP_MEMORY_SCOPE_AGENT);
      dot += zz * cls_w[lane * 8 + j];
    }
#pragma unroll
    for (int off = 32; off; off >>= 1) dot += __shfl_xor(dot, off);
    if (lane == 0) out_y[0] = dot + cls_b[0];
  }
}

// ---------------------------------------------------------------------------
// Workspace layout (bytes), max end = 69,275,904:
//   A1dot/A1ss overlay wkbf tail region (dead after gemm_k; zeroed in node 3)
//   qtanh overlays kbf+ktanh (dead after reduce_v)
// ---------------------------------------------------------------------------
#define OFF_WQBF 0u
#define OFF_WKBF 1048576u
#define OFF_A1D  1048576u      // 64 KB (over wkbf)
#define OFF_A1S  1114112u      // 64 KB
#define OFF_QBF  2097152u
#define OFF_A1   35651584u
#define OFF_V    35717120u
#define OFF_Z    35719168u
#define OFF_SC   35721216u
#define OFF_KBF  35721472u
#define OFF_KT   51968256u
#define OFF_QT   35721472u

extern "C" void kernel_launch(void* const* d_in, const int* in_sizes, int n_in,
                              void* d_out, int out_size, void* d_ws, size_t ws_size,
                              hipStream_t stream) {
  const float* query = (const float*)d_in[0];
  const float* key_x = (const float*)d_in[1];
  const float* wq_w  = (const float*)d_in[2];
  const float* wq_b  = (const float*)d_in[3];
  const float* wk_w  = (const float*)d_in[4];
  const float* wk_b  = (const float*)d_in[5];
  const float* wa_w  = (const float*)d_in[6];
  const float* wa_b  = (const float*)d_in[7];
  const float* cls_w = (const float*)d_in[8];
  const float* cls_b = (const float*)d_in[9];
  float* out = (float*)d_out;

  char* ws = (char*)d_ws;
  __bf16* wqbf  = (__bf16*)(ws + OFF_WQBF);
  __bf16* wkbf  = (__bf16*)(ws + OFF_WKBF);
  float*  A1dot = (float*)(ws + OFF_A1D);
  float*  A1ss  = (float*)(ws + OFF_A1S);
  __bf16* qbf   = (__bf16*)(ws + OFF_QBF);
  float*  A1    = (float*)(ws + OFF_A1);
  float*  v     = (float*)(ws + OFF_V);
  float*  z     = (float*)(ws + OFF_Z);
  float*  scf   = (float*)(ws + OFF_SC);
  __bf16* kbf   = (__bf16*)(ws + OFF_KBF);
  float*  ktanh = (float*)(ws + OFF_KT);
  float*  qtanh = (float*)(ws + OFF_QT);
  float*  out_attn = out + 1;

  // 1: convert to bf16 (+ zero v/z/scf)
  conv_all<<<4096, 256, 0, stream>>>(query, key_x, wq_w, wk_w,
                                     qbf, kbf, wqbf, wkbf, (unsigned*)v);

  // 2: ktanh = tanh(key @ wk^T + wk_b)
  gemm_bt_tanh<false><<<dim3(62, 4), 256, 0, stream>>>(
      kbf, wkbf, wk_b, ktanh, NK, nullptr, nullptr, nullptr);

  // 3: v = sum_k wa[k]*l2norm(ktanh[k,:])  (+ zero A1dot/A1ss)
  reduce_v_zero<<<64, 256, 0, stream>>>(ktanh, wa_w, v, NK, (uint2*)A1dot);

  // 4: qtanh = tanh(query @ wq^T + wq_b) with fused A1 partial dot/ss
  gemm_bt_tanh<true><<<dim3(128, 4), 256, 0, stream>>>(
      qbf, wqbf, wq_b, qtanh, NQ, v, A1dot, A1ss);

  // 5: finalize A1 + exact threshold + S (single block)
  select_kernel<<<1, 1024, 0, stream>>>(A1dot, A1ss, wa_b, A1, scf);

  // 6: normalized attn, z accumulation, last-block y
  expz<<<128, 256, 0, stream>>>(A1, qtanh, scf, out_attn, z, cls_w, cls_b, out);
}